// Round 1
// baseline (268.934 us; speedup 1.0000x reference)
//
#include <hip/hip_runtime.h>
#include <hip/hip_bf16.h>

// Embedding gather: out[token, :] = weight[idx[token], :]
// idx:    (B*S)            int32, B=4, S=4096  -> 16384 tokens
// weight: (VOCAB, HIDDEN)  fp32,  VOCAB=50257, HIDDEN=1024
// out:    (B*S, HIDDEN)    fp32
//
// One block per token, 256 threads, each thread moves one float4 (16 B).
// Row stride 1024 floats = 4096 B (16B-aligned), so loads/stores are fully
// coalesced dwordx4.

#define HIDDEN 1024
#define VEC4_PER_ROW (HIDDEN / 4)  // 256

__global__ __launch_bounds__(256) void embed_gather_kernel(
    const int* __restrict__ idx,
    const float* __restrict__ weight,
    float* __restrict__ out)
{
    const int token = blockIdx.x;
    const int row = idx[token];  // wave-uniform -> scalar load + broadcast

    const float4* __restrict__ src =
        reinterpret_cast<const float4*>(weight + (size_t)row * HIDDEN);
    float4* __restrict__ dst =
        reinterpret_cast<float4*>(out + (size_t)token * HIDDEN);

    dst[threadIdx.x] = src[threadIdx.x];
}

extern "C" void kernel_launch(void* const* d_in, const int* in_sizes, int n_in,
                              void* d_out, int out_size, void* d_ws, size_t ws_size,
                              hipStream_t stream) {
    const int* idx = (const int*)d_in[0];          // (B*S) = 16384
    const float* weight = (const float*)d_in[1];   // 50257 * 1024
    float* out = (float*)d_out;                    // 16384 * 1024

    const int n_tokens = in_sizes[0];              // 16384

    embed_gather_kernel<<<n_tokens, 256, 0, stream>>>(idx, weight, out);
}